// Round 6
// baseline (142.010 us; speedup 1.0000x reference)
//
#include <hip/hip_runtime.h>
#include <hip/hip_cooperative_groups.h>
#include <cmath>

namespace cg = cooperative_groups;

#define S_SUB 512
#define T_TR  8192
#define D_IN  8
#define NSEG  4            // segments per subject
#define SEGT  (T_TR/NSEG)  // 2048 trials per segment
#define BLK   256          // threads per block
#define CH    (SEGT/BLK)   // 8 trials per thread
#define NW    (BLK/64)     // 4 waves per block

typedef float f4 __attribute__((ext_vector_type(4)));

// ---------------------------------------------------------------------------
// Kernel 1 (tiny): per-subject parameter chain in f64 (erfcinv isolated here
// to keep the streaming kernel under its 64-VGPR occupancy cap).
// ---------------------------------------------------------------------------
__global__ void setup_kernel(const float* __restrict__ u_a,
                             const float* __restrict__ sigmasq,
                             const float* __restrict__ eps_mu,
                             const float* __restrict__ eps_x0,
                             double Fa, double dF,
                             double* __restrict__ params) {   // [S][4]
    int s = blockIdx.x * blockDim.x + threadIdx.x;
    if (s >= S_SUB) return;
    const double RS2 = 0.7071067811865476;     // 1/sqrt(2)
    const double S2  = 1.4142135623730951;     // sqrt(2)
    const double ISQ = 0.3989422804014327;     // 1/sqrt(2*pi)
    double p = fma((double)u_a[s], dF, Fa);
    double z = -S2 * erfcinv(2.0 * p);
    #pragma unroll
    for (int it = 0; it < 2; ++it) {           // Newton polish: Phi(z)=p
        double F   = 0.5 * erfc(-z * RS2);
        double pdf = exp(-0.5 * z * z) * ISQ;
        z -= (F - p) / pdf;
    }
    double a  = 0.99 + 0.1 * z;
    double mu = (double)eps_mu[s];
    double b  = mu * (1.0 - a);
    double x0 = mu + (double)eps_x0[s];
    double sd = sqrt((double)sigmasq[s]);
    params[4*s+0] = a;
    params[4*s+1] = b;
    params[4*s+2] = sd;
    params[4*s+3] = x0;
}

// ---------------------------------------------------------------------------
// Shared phase B: coalesced streaming of inputs/u_bern + logits + Bernoulli.
// t0 = g*1024 + tid*4 -> 16 B/lane loads AND stores, fully coalesced.
// f64 math identical to the validated round-4 kernel.
// ---------------------------------------------------------------------------
__device__ __forceinline__ void phaseB(
    const float* __restrict__ inputs,
    const float* __restrict__ eps_w,
    const float* __restrict__ u_bern,
    const double* __restrict__ xs,     // shared transpose buffer (pad CH+1)
    size_t segbase, int s, int tid,
    float* __restrict__ out_x,
    float* __restrict__ out_y)
{
    const float* wp = eps_w + s * D_IN;
    const double w0 = (double)wp[0], w1 = (double)wp[1];
    const double w2 = (double)wp[2], w3 = (double)wp[3];
    const double w4 = (double)wp[4], w5 = (double)wp[5];
    const double w6 = (double)wp[6], w7 = (double)wp[7];

    const f4* in4 = (const f4*)(inputs + segbase * D_IN);
    #pragma unroll
    for (int g = 0; g < CH/4; ++g) {
        const int t0 = g * (BLK * 4) + tid * 4;
        f4 ub = *(const f4*)(u_bern + segbase + t0);
        float ubk[4]; ubk[0]=ub.x; ubk[1]=ub.y; ubk[2]=ub.z; ubk[3]=ub.w;
        float xk[4], yk[4];
        #pragma unroll
        for (int k = 0; k < 4; ++k) {
            const int t = t0 + k;
            f4 i0 = in4[2*t];
            f4 i1 = in4[2*t+1];
            double xv = xs[(t >> 3) * (CH + 1) + (t & 7)];
            double dot = fma((double)i0.x, w0,
                         fma((double)i0.y, w1,
                         fma((double)i0.z, w2,
                         fma((double)i0.w, w3,
                         fma((double)i1.x, w4,
                         fma((double)i1.y, w5,
                         fma((double)i1.z, w6, (double)i1.w * w7)))))));
            double L = xv + dot;
            double E = exp(-L);
            yk[k] = ((double)ubk[k] * (1.0 + E) < 1.0) ? 1.0f : 0.0f;
            xk[k] = (float)xv;
        }
        f4 vx; vx.x=xk[0]; vx.y=xk[1]; vx.z=xk[2]; vx.w=xk[3];
        f4 vy; vy.x=yk[0]; vy.y=yk[1]; vy.z=yk[2]; vy.w=yk[3];
        *(f4*)(out_x + segbase + t0) = vx;
        *(f4*)(out_y + segbase + t0) = vy;
    }
}

// ---------------------------------------------------------------------------
// Kernel 2 (cooperative, single pass): block (s,seg) scans its segment, keeps
// per-thread inclusive scan state in REGISTERS across grid.sync(); publishes
// its segment composite before the sync, chains predecessors' composites
// after it. eps_x is read exactly once grid-wide; one launch, no bubbles.
// ---------------------------------------------------------------------------
__global__ __launch_bounds__(BLK, 8) void coop_kernel(
    const float* __restrict__ inputs,
    const float* __restrict__ eps_w,
    const float* __restrict__ eps_x,
    const float* __restrict__ u_bern,
    const double* __restrict__ params,
    double2* __restrict__ comp,        // [NSEG-1][S]
    float* __restrict__ out_x,
    float* __restrict__ out_y)
{
    const int bid  = blockIdx.x;
    const int s    = bid >> 2;
    const int seg  = bid & 3;
    const int tid  = threadIdx.x;
    const int lane = tid & 63;
    const int wid  = tid >> 6;

    __shared__ double2 wtot[NW];
    __shared__ double  xs[BLK * (CH + 1)];   // pad-9 transpose buffer (18 KiB)

    const size_t segbase = (size_t)s * T_TR + (size_t)seg * SEGT;
    const size_t base    = segbase + (size_t)tid * CH;

    const f4* e4 = (const f4*)(eps_x + base);
    f4 o0 = e4[0];
    f4 o1 = e4[1];

    const double a  = params[4*s+0];
    const double b  = params[4*s+1];
    const double sd = params[4*s+2];

    float ev[CH];
    ev[0]=o0.x; ev[1]=o0.y; ev[2]=o0.z; ev[3]=o0.w;
    ev[4]=o1.x; ev[5]=o1.y; ev[6]=o1.z; ev[7]=o1.w;

    // local affine compose over the chunk
    double A = 1.0, Bv = 0.0;
    #pragma unroll
    for (int j = 0; j < CH; ++j) {
        double c = fma(sd, (double)ev[j], b);
        Bv = fma(a, Bv, c);
        A *= a;
    }
    // inclusive wave scan
    #pragma unroll
    for (int off = 1; off < 64; off <<= 1) {
        double pA = __shfl_up(A, off);
        double pB = __shfl_up(Bv, off);
        if (lane >= off) {
            Bv = fma(A, pB, Bv);              // cur ∘ prev
            A  = A * pA;
        }
    }
    if (lane == 63) wtot[wid] = make_double2(A, Bv);
    __syncthreads();

    // publish this segment's full composite (thread 0) for successors
    if (tid == 0 && seg < NSEG - 1) {
        double TA = wtot[0].x, TB = wtot[0].y;
        #pragma unroll
        for (int w = 1; w < NW; ++w) {
            TB = fma(wtot[w].x, TB, wtot[w].y);
            TA = wtot[w].x * TA;
        }
        comp[seg * S_SUB + s] = make_double2(TA, TB);
    }

    // per-thread exclusive prefix map (registers persist across the sync)
    double PA = 1.0, PB = 0.0;
    for (int w = 0; w < wid; ++w) {
        double2 t = wtot[w];
        PB = fma(t.x, PB, t.y);
        PA = t.x * PA;
    }
    double eA = __shfl_up(A, 1);
    double eB = __shfl_up(Bv, 1);
    if (lane == 0) { eA = 1.0; eB = 0.0; }
    double EB = fma(eA, PB, eB);
    double EA = eA * PA;

    // grid-wide barrier: all composites published & visible after this
    cg::this_grid().sync();

    // chain predecessors' composites -> segment seed
    double xseed = params[4*s+3];
    #pragma unroll
    for (int p = 0; p < NSEG - 1; ++p) {
        if (p < seg) {                        // block-uniform
            double2 c = comp[p * S_SUB + s];
            xseed = fma(c.x, xseed, c.y);
        }
    }
    double x = fma(EA, xseed, EB);            // x at start of this chunk

    // replay: deposit x_t (f64, pre-update) into LDS transpose buffer
    #pragma unroll
    for (int j = 0; j < CH; ++j) {
        xs[tid * (CH + 1) + j] = x;
        double c = fma(sd, (double)ev[j], b);
        x = fma(a, x, c);
    }
    __syncthreads();

    phaseB(inputs, eps_w, u_bern, xs, segbase, s, tid, out_x, out_y);
}

// ---------------------------------------------------------------------------
// Fallback path (captured only if the cooperative launch is rejected):
// round-4's validated compose + fused pipeline.
// ---------------------------------------------------------------------------
__global__ __launch_bounds__(BLK) void compose2_kernel(
    const float* __restrict__ eps_x,
    const double* __restrict__ params,
    double2* __restrict__ comp)        // [NSEG-1][S]
{
    const int bid = blockIdx.x;
    const int s   = bid / 3;
    const int seg = bid % 3;
    const int tid  = threadIdx.x;
    const int lane = tid & 63;
    const int wid  = tid >> 6;

    __shared__ double2 wtot[NW];
    const size_t base = (size_t)s * T_TR + (size_t)seg * SEGT + (size_t)tid * CH;

    const f4* e4 = (const f4*)(eps_x + base);
    f4 v0 = e4[0];
    f4 v1 = e4[1];

    const double a  = params[4*s+0];
    const double b  = params[4*s+1];
    const double sd = params[4*s+2];

    float ev[CH];
    ev[0]=v0.x; ev[1]=v0.y; ev[2]=v0.z; ev[3]=v0.w;
    ev[4]=v1.x; ev[5]=v1.y; ev[6]=v1.z; ev[7]=v1.w;

    double A = 1.0, Bv = 0.0;
    #pragma unroll
    for (int j = 0; j < CH; ++j) {
        double c = fma(sd, (double)ev[j], b);
        Bv = fma(a, Bv, c);
        A *= a;
    }
    #pragma unroll
    for (int off = 1; off < 64; off <<= 1) {
        double pA = __shfl_down(A, off);
        double pB = __shfl_down(Bv, off);
        Bv = fma(pA, Bv, pB);                 // later ∘ earlier
        A  = pA * A;
    }
    if (lane == 0) wtot[wid] = make_double2(A, Bv);
    __syncthreads();
    if (tid == 0) {
        double CA = wtot[0].x, CB = wtot[0].y;
        #pragma unroll
        for (int w = 1; w < NW; ++w) {
            CB = fma(wtot[w].x, CB, wtot[w].y);
            CA = wtot[w].x * CA;
        }
        comp[seg * S_SUB + s] = make_double2(CA, CB);
    }
}

__global__ __launch_bounds__(BLK, 8) void fused2_kernel(
    const float* __restrict__ inputs,
    const float* __restrict__ eps_w,
    const float* __restrict__ eps_x,
    const float* __restrict__ u_bern,
    const double* __restrict__ params,
    const double2* __restrict__ comp,
    float* __restrict__ out_x,
    float* __restrict__ out_y)
{
    const int bid  = blockIdx.x;
    const int s    = bid >> 2;
    const int seg  = bid & 3;
    const int tid  = threadIdx.x;
    const int lane = tid & 63;
    const int wid  = tid >> 6;

    __shared__ double2 wtot[NW];
    __shared__ double  xs[BLK * (CH + 1)];

    const size_t segbase = (size_t)s * T_TR + (size_t)seg * SEGT;
    const size_t base    = segbase + (size_t)tid * CH;

    const f4* e4 = (const f4*)(eps_x + base);
    f4 o0 = e4[0];
    f4 o1 = e4[1];

    const double a  = params[4*s+0];
    const double b  = params[4*s+1];
    const double sd = params[4*s+2];
    double xseed    = params[4*s+3];
    for (int i = 0; i < seg; ++i) {
        double2 c = comp[i * S_SUB + s];
        xseed = fma(c.x, xseed, c.y);
    }

    float ev[CH];
    ev[0]=o0.x; ev[1]=o0.y; ev[2]=o0.z; ev[3]=o0.w;
    ev[4]=o1.x; ev[5]=o1.y; ev[6]=o1.z; ev[7]=o1.w;

    double A = 1.0, Bv = 0.0;
    #pragma unroll
    for (int j = 0; j < CH; ++j) {
        double c = fma(sd, (double)ev[j], b);
        Bv = fma(a, Bv, c);
        A *= a;
    }
    #pragma unroll
    for (int off = 1; off < 64; off <<= 1) {
        double pA = __shfl_up(A, off);
        double pB = __shfl_up(Bv, off);
        if (lane >= off) {
            Bv = fma(A, pB, Bv);
            A  = A * pA;
        }
    }
    if (lane == 63) wtot[wid] = make_double2(A, Bv);
    __syncthreads();

    double PA = 1.0, PB = 0.0;
    for (int w = 0; w < wid; ++w) {
        double2 t = wtot[w];
        PB = fma(t.x, PB, t.y);
        PA = t.x * PA;
    }
    double eA = __shfl_up(A, 1);
    double eB = __shfl_up(Bv, 1);
    if (lane == 0) { eA = 1.0; eB = 0.0; }
    double EB = fma(eA, PB, eB);
    double EA = eA * PA;
    double x  = fma(EA, xseed, EB);

    #pragma unroll
    for (int j = 0; j < CH; ++j) {
        xs[tid * (CH + 1) + j] = x;
        double c = fma(sd, (double)ev[j], b);
        x = fma(a, x, c);
    }
    __syncthreads();

    phaseB(inputs, eps_w, u_bern, xs, segbase, s, tid, out_x, out_y);
}

extern "C" void kernel_launch(void* const* d_in, const int* in_sizes, int n_in,
                              void* d_out, int out_size, void* d_ws, size_t ws_size,
                              hipStream_t stream) {
    const float* inputs  = (const float*)d_in[0];   // [S,T,D]
    const float* eps_w   = (const float*)d_in[1];   // [S,D]
    const float* u_a     = (const float*)d_in[2];   // [S]
    const float* sigmasq = (const float*)d_in[3];   // [S]
    const float* eps_mu  = (const float*)d_in[4];   // [S]
    const float* eps_x0  = (const float*)d_in[5];   // [S]
    const float* eps_x   = (const float*)d_in[6];   // [S,T]
    const float* u_bern  = (const float*)d_in[7];   // [S,T]

    float*   out    = (float*)d_out;                // [x | y] f32
    float*   out_x  = out;
    float*   out_y  = out + (size_t)S_SUB * T_TR;
    double*  params = (double*)d_ws;                          // 16 KiB
    double2* comp   = (double2*)((char*)d_ws + 16*1024);      // 24 KiB used

    // input-independent truncation constants (host f64 libm)
    const double RS2 = 0.7071067811865476;
    const double Fa  = 0.5 * erfc(9.9 * RS2);       // Phi(-9.9)
    const double Fb  = 0.5 * erfc(-0.1 * RS2);      // Phi(0.1)
    const double dF  = Fb - Fa;

    setup_kernel<<<2, 256, 0, stream>>>(u_a, sigmasq, eps_mu, eps_x0, Fa, dF, params);

    void* args[] = { (void*)&inputs, (void*)&eps_w, (void*)&eps_x, (void*)&u_bern,
                     (void*)&params, (void*)&comp, (void*)&out_x, (void*)&out_y };
    hipError_t err = hipLaunchCooperativeKernel(
        (const void*)coop_kernel, dim3(S_SUB * NSEG), dim3(BLK), args, 0, stream);

    if (err != hipSuccess) {
        // fallback: validated round-4 two-kernel pipeline
        compose2_kernel<<<S_SUB*(NSEG-1), BLK, 0, stream>>>(eps_x, params, comp);
        fused2_kernel<<<S_SUB*NSEG, BLK, 0, stream>>>(inputs, eps_w, eps_x, u_bern,
                                                      params, comp, out_x, out_y);
    }
}

// Round 7
// 39.286 us; speedup vs baseline: 3.6148x; 3.6148x over previous
//
#include <hip/hip_runtime.h>
#include <cmath>

#define S_SUB 512
#define T_TR  8192
#define D_IN  8
#define BLK   1024         // one block per subject
#define CH    (T_TR/BLK)   // 8 trials per thread
#define NW    (BLK/64)     // 16 waves per block

typedef float f4 __attribute__((ext_vector_type(4)));

// ---------------------------------------------------------------------------
// Kernel 1 (tiny): per-subject parameter chain in f64 (erfcinv isolated here
// so the streaming kernel stays under its 64-VGPR occupancy cap).
// Fa = Phi(-9.9), dF = Phi(0.1)-Phi(-9.9) are host-computed constants.
// ---------------------------------------------------------------------------
__global__ void setup_kernel(const float* __restrict__ u_a,
                             const float* __restrict__ sigmasq,
                             const float* __restrict__ eps_mu,
                             const float* __restrict__ eps_x0,
                             double Fa, double dF,
                             double* __restrict__ params) {   // [S][4]
    int s = blockIdx.x * blockDim.x + threadIdx.x;
    if (s >= S_SUB) return;
    const double RS2 = 0.7071067811865476;     // 1/sqrt(2)
    const double S2  = 1.4142135623730951;     // sqrt(2)
    const double ISQ = 0.3989422804014327;     // 1/sqrt(2*pi)
    double p = fma((double)u_a[s], dF, Fa);
    double z = -S2 * erfcinv(2.0 * p);
    #pragma unroll
    for (int it = 0; it < 2; ++it) {           // Newton polish: Phi(z)=p
        double F   = 0.5 * erfc(-z * RS2);
        double pdf = exp(-0.5 * z * z) * ISQ;
        z -= (F - p) / pdf;
    }
    double a  = 0.99 + 0.1 * z;
    double mu = (double)eps_mu[s];
    double b  = mu * (1.0 - a);
    double x0 = mu + (double)eps_x0[s];
    double sd = sqrt((double)sigmasq[s]);
    params[4*s+0] = a;
    params[4*s+1] = b;
    params[4*s+2] = sd;
    params[4*s+3] = x0;
}

// ---------------------------------------------------------------------------
// Kernel 2: one block per SUBJECT (1024 threads, whole T=8192 scan in-block).
// No inter-block dependencies at all: 6-step wave scan + 16-wave cross-wave
// prefix (2 barriers), f64 replay into a pad-9 LDS transpose buffer, then
// coalesced phase-B streaming (trial = j*BLK + tid) of inputs/u_bern with
// fused logits + Bernoulli. eps_x is read exactly once grid-wide.
// LDS 73.9 KiB -> 2 blocks/CU x 16 waves = 32 waves/CU (100% occupancy).
// ---------------------------------------------------------------------------
__global__ __launch_bounds__(BLK, 8) void mono_kernel(
    const float* __restrict__ inputs,
    const float* __restrict__ eps_w,
    const float* __restrict__ eps_x,
    const float* __restrict__ u_bern,
    const double* __restrict__ params,
    float* __restrict__ out_x,
    float* __restrict__ out_y)
{
    const int s    = blockIdx.x;
    const int tid  = threadIdx.x;
    const int lane = tid & 63;
    const int wid  = tid >> 6;

    __shared__ double2 wtot[NW];
    __shared__ double  xs[BLK * (CH + 1)];   // pad-9 transpose buffer (73.7 KiB)

    const size_t subjbase = (size_t)s * T_TR;
    const size_t base     = subjbase + (size_t)tid * CH;

    // ---- own chunk of eps_x (the only eps_x read) ----
    const f4* e4 = (const f4*)(eps_x + base);
    f4 o0 = e4[0];
    f4 o1 = e4[1];

    const double a  = params[4*s+0];
    const double b  = params[4*s+1];
    const double sd = params[4*s+2];
    const double x0 = params[4*s+3];

    float ev[CH];
    ev[0]=o0.x; ev[1]=o0.y; ev[2]=o0.z; ev[3]=o0.w;
    ev[4]=o1.x; ev[5]=o1.y; ev[6]=o1.z; ev[7]=o1.w;

    // ---- phase 1: local affine compose over the chunk ----
    double A = 1.0, Bv = 0.0;
    #pragma unroll
    for (int j = 0; j < CH; ++j) {
        double c = fma(sd, (double)ev[j], b);
        Bv = fma(a, Bv, c);
        A *= a;
    }

    // ---- phase 2a: inclusive wave scan (shfl_up Hillis-Steele) ----
    #pragma unroll
    for (int off = 1; off < 64; off <<= 1) {
        double pA = __shfl_up(A, off);
        double pB = __shfl_up(Bv, off);
        if (lane >= off) {
            Bv = fma(A, pB, Bv);              // cur ∘ prev
            A  = A * pA;
        }
    }
    if (lane == 63) wtot[wid] = make_double2(A, Bv);
    __syncthreads();

    // ---- phase 2b: exclusive cross-wave prefix (16 waves) ----
    double PA = 1.0, PB = 0.0;
    for (int w = 0; w < wid; ++w) {
        double2 t = wtot[w];
        PB = fma(t.x, PB, t.y);
        PA = t.x * PA;
    }
    double eA = __shfl_up(A, 1);
    double eB = __shfl_up(Bv, 1);
    if (lane == 0) { eA = 1.0; eB = 0.0; }
    double EB = fma(eA, PB, eB);
    double EA = eA * PA;
    double x  = fma(EA, x0, EB);              // x at start of this chunk

    // ---- phase A replay: deposit x_t (f64, pre-update) into LDS ----
    #pragma unroll
    for (int j = 0; j < CH; ++j) {
        xs[tid * (CH + 1) + j] = x;
        double c = fma(sd, (double)ev[j], b);
        x = fma(a, x, c);
    }
    __syncthreads();

    // ---- phase B: coalesced streaming (trial = j*BLK + tid) ----
    const float* wp = eps_w + s * D_IN;
    const double w0 = (double)wp[0], w1 = (double)wp[1];
    const double w2 = (double)wp[2], w3 = (double)wp[3];
    const double w4 = (double)wp[4], w5 = (double)wp[5];
    const double w6 = (double)wp[6], w7 = (double)wp[7];

    float uv[CH];
    #pragma unroll
    for (int j = 0; j < CH; ++j)
        uv[j] = u_bern[subjbase + j * BLK + tid];

    const f4* in4 = (const f4*)(inputs + subjbase * D_IN);
    #pragma unroll
    for (int j = 0; j < CH; ++j) {
        const int t = j * BLK + tid;
        f4 i0 = in4[2*t];
        f4 i1 = in4[2*t + 1];
        double xv = xs[(t >> 3) * (CH + 1) + (t & 7)];
        double dot = fma((double)i0.x, w0,
                     fma((double)i0.y, w1,
                     fma((double)i0.z, w2,
                     fma((double)i0.w, w3,
                     fma((double)i1.x, w4,
                     fma((double)i1.y, w5,
                     fma((double)i1.z, w6, (double)i1.w * w7)))))));
        double L = xv + dot;
        double E = exp(-L);
        out_y[subjbase + t] = ((double)uv[j] * (1.0 + E) < 1.0) ? 1.0f : 0.0f;
        out_x[subjbase + t] = (float)xv;
    }
}

extern "C" void kernel_launch(void* const* d_in, const int* in_sizes, int n_in,
                              void* d_out, int out_size, void* d_ws, size_t ws_size,
                              hipStream_t stream) {
    const float* inputs  = (const float*)d_in[0];   // [S,T,D]
    const float* eps_w   = (const float*)d_in[1];   // [S,D]
    const float* u_a     = (const float*)d_in[2];   // [S]
    const float* sigmasq = (const float*)d_in[3];   // [S]
    const float* eps_mu  = (const float*)d_in[4];   // [S]
    const float* eps_x0  = (const float*)d_in[5];   // [S]
    const float* eps_x   = (const float*)d_in[6];   // [S,T]
    const float* u_bern  = (const float*)d_in[7];   // [S,T]

    float*  out    = (float*)d_out;                 // [x | y] f32
    double* params = (double*)d_ws;                 // 16 KiB

    // input-independent truncation constants (host f64 libm)
    const double RS2 = 0.7071067811865476;
    const double Fa  = 0.5 * erfc(9.9 * RS2);       // Phi(-9.9)
    const double Fb  = 0.5 * erfc(-0.1 * RS2);      // Phi(0.1)
    const double dF  = Fb - Fa;

    setup_kernel<<<2, 256, 0, stream>>>(u_a, sigmasq, eps_mu, eps_x0, Fa, dF, params);
    mono_kernel<<<S_SUB, BLK, 0, stream>>>(inputs, eps_w, eps_x, u_bern, params,
                                           out, out + (size_t)S_SUB * T_TR);
}